// Round 17
// baseline (37.802 us; speedup 1.0000x reference)
//
#include <hip/hip_runtime.h>
#include <hip/hip_bf16.h>

#define Nn  2048
#define Aa  256
#define Cc  100
#define LAT 128
#define BN_EPS 1e-5f

// ws layout in floats (everything fully overwritten each call -> no zeroing)
#define OFF_HB   0                         // h bf16 [2048][128] = 131072 floats
#define OFF_SUMS (OFF_HB + Nn*LAT/2)       // 128 blocks * 256 f32
#define OFF_SP   (OFF_SUMS + 128*256)      // Spart [2][100][100] f32
#define OFF_W2B  (OFF_SP + 2*Cc*Cc)        // W2 bf16 [256][128]
#define OFF_WFB  (OFF_W2B + Aa*LAT/2)      // Wfc bf16 padded [128][256]

typedef __attribute__((ext_vector_type(8))) short bf16x8;
typedef __attribute__((ext_vector_type(4))) float f32x4;

__device__ __forceinline__ short f2bf(float f) {
    return (short)__bfloat16_as_ushort(__float2bfloat16(f));
}
__device__ __forceinline__ float bf2f(short h) {
    return __uint_as_float(((unsigned)(unsigned short)h) << 16);
}

#define DPITCH 264     // bf16 pitch: 528 B
#define FPITCH 264
#define NWG_A  330     // 200 ks + 128 k1 + 2 conv

// LDS carve for ks blocks: D(112 rows) | covT(32 rows) | red[4][112]
#define KS_DBYTES   (112 * DPITCH * 2)           // 59,136
#define KS_CBYTES   (32 * DPITCH * 2)            // 16,896
#define KS_SMEM     (KS_DBYTES + KS_CBYTES + 4 * 112 * 4)  // 77,824 -> 2 blocks/CU

// ---- ks body v3: block (k, bh). ch halves MERGED: each cov panel (128x256,
// 128 KB) is staged ONCE per (k,bh) -> total cov HBM = 26 MB (halved vs r15).
// Coalesced staging: one wave-instruction = one contiguous 1KB cov row.
// Waves split the a-axis; per-panel partial P folded into sacc; cross-wave
// a-sum via red[]. Per-output arithmetic identical to r15 (same bf16/f32 ops).
__device__ __forceinline__ void ks_body3(
    const float* __restrict__ Wfc, const float* __restrict__ cov,
    float* __restrict__ Spart, short* Dlds, short* covT, float (*red)[112],
    int k, int bh, int t, int w, int il, int q)
{
    const float* covk = cov + (size_t)k * (Aa * Aa);
    const int lane = t & 63;

    {   // stage D rows 0..111 (bf16), rows >= Cc zero; coalesced
        const int c4 = t & 63;
        float4 wk = *(const float4*)&Wfc[(size_t)k * Aa + c4 * 4];
#pragma unroll
        for (int j = 0; j < 28; j++) {
            int row = (t >> 6) + j * 4;
            short4 o = {0, 0, 0, 0};
            if (row < Cc) {
                float4 v = *(const float4*)&Wfc[(size_t)row * Aa + c4 * 4];
                o.x = f2bf(v.x - wk.x); o.y = f2bf(v.y - wk.y);
                o.z = f2bf(v.z - wk.z); o.w = f2bf(v.w - wk.w);
            }
            *(short4*)&Dlds[row * DPITCH + c4 * 4] = o;
        }
    }

    float4 pre[8];
#pragma unroll
    for (int i = 0; i < 8; i++)
        pre[i] = *(const float4*)&covk[(size_t)(bh * 128 + w * 8 + i) * Aa + lane * 4];

    __syncthreads();
#pragma unroll
    for (int i = 0; i < 8; i++) {
        short4 o = {f2bf(pre[i].x), f2bf(pre[i].y), f2bf(pre[i].z), f2bf(pre[i].w)};
        *(short4*)&covT[(w * 8 + i) * DPITCH + lane * 4] = o;
    }
    __syncthreads();

    float sacc[7][4];
#pragma unroll
    for (int m = 0; m < 7; m++)
#pragma unroll
        for (int r = 0; r < 4; r++) sacc[m][r] = 0.f;

    for (int p = 0; p < 4; p++) {
        if (p < 3) {                         // issue next panel loads early
#pragma unroll
            for (int i = 0; i < 8; i++)
                pre[i] = *(const float4*)&covk[(size_t)(bh * 128 + (p + 1) * 32 + w * 8 + i) * Aa + lane * 4];
        }

        f32x4 acc[7][2];
#pragma unroll
        for (int m = 0; m < 7; m++) {
            acc[m][0] = (f32x4){0.f,0.f,0.f,0.f};
            acc[m][1] = (f32x4){0.f,0.f,0.f,0.f};
        }
#pragma unroll
        for (int sg = 0; sg < 2; sg++) {
            const int a0 = w * 64 + sg * 32 + q * 8;     // wave-private a-range
            bf16x8 bm0 = *(bf16x8*)&covT[il * DPITCH + a0];
            bf16x8 bm1 = *(bf16x8*)&covT[(16 + il) * DPITCH + a0];
#pragma unroll
            for (int m = 0; m < 7; m++) {
                bf16x8 am = *(bf16x8*)&Dlds[(m * 16 + il) * DPITCH + a0];
                acc[m][0] = __builtin_amdgcn_mfma_f32_16x16x32_bf16(am, bm0, acc[m][0], 0, 0, 0);
                acc[m][1] = __builtin_amdgcn_mfma_f32_16x16x32_bf16(am, bm1, acc[m][1], 0, 0, 0);
            }
        }
#pragma unroll
        for (int m = 0; m < 7; m++)
#pragma unroll
            for (int nf = 0; nf < 2; nf++) {
                const int bcol = bh * 128 + p * 32 + nf * 16 + il;
#pragma unroll
                for (int r = 0; r < 4; r++) {
                    float dv = bf2f(Dlds[(m * 16 + q * 4 + r) * DPITCH + bcol]);
                    sacc[m][r] = fmaf(dv, acc[m][nf][r], sacc[m][r]);
                }
            }
        __syncthreads();
        if (p < 3) {
#pragma unroll
            for (int i = 0; i < 8; i++) {
                short4 o = {f2bf(pre[i].x), f2bf(pre[i].y), f2bf(pre[i].z), f2bf(pre[i].w)};
                *(short4*)&covT[(w * 8 + i) * DPITCH + lane * 4] = o;
            }
            __syncthreads();
        }
    }

#pragma unroll
    for (int m = 0; m < 7; m++) {
#pragma unroll
        for (int r = 0; r < 4; r++) {
            float v = sacc[m][r];
            v += __shfl_xor(v, 1);
            v += __shfl_xor(v, 2);
            v += __shfl_xor(v, 4);
            v += __shfl_xor(v, 8);
            if (il == 0) red[w][m * 16 + q * 4 + r] = v;
        }
    }
    __syncthreads();
    if (t < 112 && t < Cc)
        Spart[bh * (Cc * Cc) + k * Cc + t] =
            red[0][t] + red[1][t] + red[2][t] + red[3][t];
}

// ---------------- A: fused { ks (k,bh) | k1 tiles | weight conversions } ------
// bid 0..199   : ks  (k = bid>>1, bh = bid&1) -> Spart[bh]
// bid 200..327 : k1 16-row tile -> hB + per-block stats (depth-2 prefetch)
// bid 328      : W2 -> bf16     bid 329 : Wfc -> bf16 padded [128][256]
__global__ __launch_bounds__(256) void kA(
    const float* __restrict__ s, const float* __restrict__ W1,
    const float* __restrict__ b1, const float* __restrict__ Wfc,
    const float* __restrict__ W2, const float* __restrict__ cov,
    short* __restrict__ hB, float* __restrict__ sums, float* __restrict__ Spart,
    short* __restrict__ W2b, short* __restrict__ Wfcb)
{
    __shared__ __align__(16) char smem[KS_SMEM];    // 77,824 B -> 2 blocks/CU
    // bijective XCD swizzle: nwg=330, q=41, r=2 (m204)
    const int orig = blockIdx.x;
    const int xcd  = orig % 8;
    const int bid  = (xcd < 2 ? xcd * 42 : 2 * 42 + (xcd - 2) * 41) + orig / 8;
    const int t = threadIdx.x;
    const int w = t >> 6, l = t & 63, il = l & 15, q = l >> 4;

    if (bid < 200) {
        short* Dlds = (short*)smem;
        short* covT = (short*)(smem + KS_DBYTES);
        float (*red)[112] = (float(*)[112])(smem + KS_DBYTES + KS_CBYTES);
        ks_body3(Wfc, cov, Spart, Dlds, covT, red, bid >> 1, bid & 1, t, w, il, q);
    } else if (bid < 328) {
        // ---- k1 tile: h = s @ W1^T + b1, per-block stats, depth-2 prefetch ----
        const int bid2 = bid - 200;
        const int row0 = bid2 * 16;
        const int colw = w * 32;

        f32x4 acc[2];
        acc[0] = (f32x4){0.f,0.f,0.f,0.f};
        acc[1] = (f32x4){0.f,0.f,0.f,0.f};

        const float* arow = s  + (size_t)(row0 + il) * Aa;
        const float* bp0  = W1 + (size_t)(colw + il) * Aa;
        const float* bp1  = W1 + (size_t)(colw + 16 + il) * Aa;

        float4 pu0 = *(const float4*)&arow[q * 8];
        float4 pu1 = *(const float4*)&arow[q * 8 + 4];
        float4 pv0 = *(const float4*)&bp0[q * 8];
        float4 pv1 = *(const float4*)&bp0[q * 8 + 4];
        float4 px0 = *(const float4*)&bp1[q * 8];
        float4 px1 = *(const float4*)&bp1[q * 8 + 4];

#pragma unroll
        for (int ks = 0; ks < 8; ks++) {
            const float4 u0 = pu0, u1 = pu1, v0 = pv0, v1 = pv1, x0 = px0, x1 = px1;
            if (ks < 7) {
                const int k1n = (ks + 1) * 32 + q * 8;
                pu0 = *(const float4*)&arow[k1n];
                pu1 = *(const float4*)&arow[k1n + 4];
                pv0 = *(const float4*)&bp0[k1n];
                pv1 = *(const float4*)&bp0[k1n + 4];
                px0 = *(const float4*)&bp1[k1n];
                px1 = *(const float4*)&bp1[k1n + 4];
            }
            bf16x8 am;
            am[0]=f2bf(u0.x); am[1]=f2bf(u0.y); am[2]=f2bf(u0.z); am[3]=f2bf(u0.w);
            am[4]=f2bf(u1.x); am[5]=f2bf(u1.y); am[6]=f2bf(u1.z); am[7]=f2bf(u1.w);
            bf16x8 bm0;
            bm0[0]=f2bf(v0.x); bm0[1]=f2bf(v0.y); bm0[2]=f2bf(v0.z); bm0[3]=f2bf(v0.w);
            bm0[4]=f2bf(v1.x); bm0[5]=f2bf(v1.y); bm0[6]=f2bf(v1.z); bm0[7]=f2bf(v1.w);
            bf16x8 bm1;
            bm1[0]=f2bf(x0.x); bm1[1]=f2bf(x0.y); bm1[2]=f2bf(x0.z); bm1[3]=f2bf(x0.w);
            bm1[4]=f2bf(x1.x); bm1[5]=f2bf(x1.y); bm1[6]=f2bf(x1.z); bm1[7]=f2bf(x1.w);
            acc[0] = __builtin_amdgcn_mfma_f32_16x16x32_bf16(am, bm0, acc[0], 0, 0, 0);
            acc[1] = __builtin_amdgcn_mfma_f32_16x16x32_bf16(am, bm1, acc[1], 0, 0, 0);
        }

#pragma unroll
        for (int n = 0; n < 2; n++) {
            const int col = colw + n * 16 + il;
            const float bias = b1[col];
            float s1 = 0.f, s2 = 0.f;
#pragma unroll
            for (int r = 0; r < 4; r++) {
                float v = acc[n][r] + bias;
                hB[(size_t)(row0 + q * 4 + r) * LAT + col] = f2bf(v);
                s1 += v; s2 += v * v;
            }
            s1 += __shfl_xor(s1, 16); s1 += __shfl_xor(s1, 32);
            s2 += __shfl_xor(s2, 16); s2 += __shfl_xor(s2, 32);
            if (q == 0) {
                sums[bid2 * 256 + col]       = s1;
                sums[bid2 * 256 + 128 + col] = s2;
            }
        }
    } else if (bid == 328) {
        for (int i = t * 4; i < Aa * LAT; i += 1024) {
            float4 v = *(const float4*)&W2[i];
            short4 o = {f2bf(v.x), f2bf(v.y), f2bf(v.z), f2bf(v.w)};
            *(short4*)&W2b[i] = o;
        }
    } else {
        for (int i = t * 4; i < 128 * Aa; i += 1024) {
            int row = i >> 8;
            short4 o = {0, 0, 0, 0};
            if (row < Cc) {
                float4 v = *(const float4*)&Wfc[i];
                o.x = f2bf(v.x); o.y = f2bf(v.y); o.z = f2bf(v.z); o.w = f2bf(v.w);
            }
            *(short4*)&Wfcb[i] = o;
        }
    }
}

// ---------------- B: fused k3+k4 per 16-row tile (round-15 verbatim) ----------
__global__ __launch_bounds__(256) void kB(
    const short* __restrict__ hB, const float* __restrict__ sums,
    const float* __restrict__ gamma, const float* __restrict__ beta,
    const short* __restrict__ W2b, const float* __restrict__ b2,
    const short* __restrict__ Wfcb, const float* __restrict__ bfc,
    const float* __restrict__ Spart, const int* __restrict__ y,
    const float* __restrict__ ratio, float* __restrict__ out)
{
    __shared__ float scL[LAT], shL[LAT];
    __shared__ float redA[512];
    __shared__ short fLDS[16 * FPITCH];
    const int t = threadIdx.x;
    const int w = t >> 6, l = t & 63, il = l & 15, q = l >> 4;
    const int row0 = blockIdx.x * 16;

    {   // BN stats: 2-way parallel partial reduce over 128 block-partials
        const int chn = t & 127, hf = t >> 7;
        float a1 = 0.f, a2 = 0.f;
#pragma unroll 16
        for (int b = hf * 64; b < hf * 64 + 64; b++) {
            a1 += sums[b * 256 + chn];
            a2 += sums[b * 256 + 128 + chn];
        }
        redA[hf * 256 + chn]       = a1;
        redA[hf * 256 + 128 + chn] = a2;
    }
    __syncthreads();
    if (t < 128) {
        float A1 = redA[t] + redA[256 + t];
        float A2 = redA[128 + t] + redA[384 + t];
        float mu  = A1 * (1.0f / Nn);
        float var = A2 * (1.0f / Nn) - mu * mu;
        float inv = rsqrtf(var + BN_EPS);
        float sc  = gamma[t] * inv;
        scL[t] = sc;
        shL[t] = beta[t] - mu * sc;
    }
    __syncthreads();

    // ---- GEMM1: f_tile = relu(bn(h_tile) @ W2^T + b2), cols w*64..+64 ----
    f32x4 acc3[4];
#pragma unroll
    for (int n = 0; n < 4; n++) acc3[n] = (f32x4){0.f,0.f,0.f,0.f};

    const short* arow = hB + (size_t)(row0 + il) * LAT;
#pragma unroll
    for (int ks = 0; ks < 4; ks++) {
        const int k0 = ks * 32 + q * 8;
        bf16x8 ha = *(const bf16x8*)&arow[k0];
        bf16x8 am;
#pragma unroll
        for (int j = 0; j < 8; j++) {
            float fv = fmaf(bf2f(ha[j]), scL[k0 + j], shL[k0 + j]);
            am[j] = f2bf(fmaxf(fv, 0.f));
        }
#pragma unroll
        for (int n = 0; n < 4; n++) {
            const int col = w * 64 + n * 16 + il;
            bf16x8 bm = *(const bf16x8*)&W2b[(size_t)col * LAT + k0];
            acc3[n] = __builtin_amdgcn_mfma_f32_16x16x32_bf16(am, bm, acc3[n], 0, 0, 0);
        }
    }
#pragma unroll
    for (int n = 0; n < 4; n++) {
        const int col = w * 64 + n * 16 + il;
        const float bias = b2[col];
#pragma unroll
        for (int r = 0; r < 4; r++) {
            float v = fmaxf(acc3[n][r] + bias, 0.f);
            fLDS[(q * 4 + r) * FPITCH + col] = f2bf(v);
        }
    }
    __syncthreads();

    // ---- GEMM2: out_tile = f_tile @ Wfc^T, cols w*32..+32 ----
    f32x4 acc4[2];
    acc4[0] = (f32x4){0.f,0.f,0.f,0.f};
    acc4[1] = (f32x4){0.f,0.f,0.f,0.f};
#pragma unroll
    for (int ks = 0; ks < 8; ks++) {
        const int k0 = ks * 32 + q * 8;
        bf16x8 am = *(const bf16x8*)&fLDS[il * FPITCH + k0];
#pragma unroll
        for (int n = 0; n < 2; n++) {
            const int col = w * 32 + n * 16 + il;      // padded rows are zero
            bf16x8 bm = *(const bf16x8*)&Wfcb[(size_t)col * Aa + k0];
            acc4[n] = __builtin_amdgcn_mfma_f32_16x16x32_bf16(am, bm, acc4[n], 0, 0, 0);
        }
    }

    const float coef = 0.5f * ratio[0];
    const int4 yv4 = *(const int4*)&y[row0 + q * 4];
    const int yr[4] = {yv4.x, yv4.y, yv4.z, yv4.w};

#pragma unroll
    for (int n = 0; n < 2; n++) {
        const int col = w * 32 + n * 16 + il;
        if (col < Cc) {
            const float bias = bfc[col];
#pragma unroll
            for (int r = 0; r < 4; r++) {
                const float* sp = &Spart[yr[r] * Cc + col];
                float sv = sp[0] + sp[Cc * Cc];
                out[(size_t)(row0 + q * 4 + r) * Cc + col] =
                    acc4[n][r] + bias + coef * sv;
            }
        }
    }
}

extern "C" void kernel_launch(void* const* d_in, const int* in_sizes, int n_in,
                              void* d_out, int out_size, void* d_ws, size_t ws_size,
                              hipStream_t stream)
{
    const float* s     = (const float*)d_in[0];
    const int*   y     = (const int*)  d_in[1];
    const float* ratio = (const float*)d_in[2];
    const float* W1    = (const float*)d_in[3];
    const float* b1    = (const float*)d_in[4];
    const float* gamma = (const float*)d_in[5];
    const float* beta  = (const float*)d_in[6];
    const float* W2    = (const float*)d_in[7];
    const float* b2    = (const float*)d_in[8];
    const float* Wfc   = (const float*)d_in[9];
    const float* bfc   = (const float*)d_in[10];
    const float* cov   = (const float*)d_in[11];
    float* out = (float*)d_out;
    float* ws  = (float*)d_ws;

    short* hB    = (short*)(ws + OFF_HB);
    float* sums  = ws + OFF_SUMS;
    float* Spart = ws + OFF_SP;
    short* W2b   = (short*)(ws + OFF_W2B);
    short* Wfcb  = (short*)(ws + OFF_WFB);

    hipLaunchKernelGGL(kA, dim3(NWG_A), dim3(256), 0, stream,
                       s, W1, b1, Wfc, W2, cov, hB, sums, Spart, W2b, Wfcb);
    hipLaunchKernelGGL(kB, dim3(128), dim3(256), 0, stream,
                       hB, sums, gamma, beta, W2b, b2, Wfcb, bfc, Spart, y, ratio, out);
}

// Round 18
// 31.211 us; speedup vs baseline: 1.2112x; 1.2112x over previous
//
#include <hip/hip_runtime.h>
#include <hip/hip_bf16.h>

#define Nn  2048
#define Aa  256
#define Cc  100
#define LAT 128
#define BN_EPS 1e-5f

// ws layout in floats (everything fully overwritten each call -> no zeroing)
#define OFF_HB   0                         // h bf16 [2048][128] = 131072 floats
#define OFF_SUMS (OFF_HB + Nn*LAT/2)       // 128 blocks * 256 f32
#define OFF_SP   (OFF_SUMS + 128*256)      // Spart [2][100][100] f32
#define OFF_W2B  (OFF_SP + 2*Cc*Cc)        // W2 bf16 [256][128]
#define OFF_WFB  (OFF_W2B + Aa*LAT/2)      // Wfc bf16 padded [128][256]

typedef __attribute__((ext_vector_type(8))) short bf16x8;
typedef __attribute__((ext_vector_type(4))) float f32x4;

__device__ __forceinline__ short f2bf(float f) {
    return (short)__bfloat16_as_ushort(__float2bfloat16(f));
}
__device__ __forceinline__ float bf2f(short h) {
    return __uint_as_float(((unsigned)(unsigned short)h) << 16);
}

#define DPITCH 264     // bf16 pitch: 528 B
#define FPITCH 264
#define NWG_A  530     // kA grid; bijective XCD swizzle over 8 XCDs (m204)

// LDS carve for ks blocks: D(64 rows) | covT(32 rows) | red
#define KS_DBYTES   (64 * DPITCH * 2)            // 33,792
#define KS_CBYTES   (32 * DPITCH * 2)            // 16,896
#define KS_SMEM     (KS_DBYTES + KS_CBYTES + 4 * 64 * 4)   // 51,712 -> 3 blocks/CU

// ---- ks body v2 (round-15 verbatim): coalesced cov panels through LDS ------
template<int MSZ>
__device__ __forceinline__ void ks_body2(
    const float* __restrict__ Wfc, const float* __restrict__ cov,
    float* __restrict__ Spart, short* Dlds, short* covT, float (*red)[64],
    int k, int ch, int bh, int t, int w, int il, int q)
{
    const float* covk = cov + (size_t)k * (Aa * Aa);
    const int c0 = ch * 64;
    const int lane = t & 63;

    {   // stage D rows (bf16), rows past Cc zero; coalesced
        const int c4 = t & 63;
        float4 wk = *(const float4*)&Wfc[(size_t)k * Aa + c4 * 4];
#pragma unroll
        for (int j = 0; j < MSZ * 4; j++) {
            int row = (t >> 6) + j * 4;
            int g = c0 + row;
            short4 o = {0, 0, 0, 0};
            if (g < Cc) {
                float4 v = *(const float4*)&Wfc[(size_t)g * Aa + c4 * 4];
                o.x = f2bf(v.x - wk.x); o.y = f2bf(v.y - wk.y);
                o.z = f2bf(v.z - wk.z); o.w = f2bf(v.w - wk.w);
            }
            *(short4*)&Dlds[row * DPITCH + c4 * 4] = o;
        }
    }

    float4 pre[8];
#pragma unroll
    for (int i = 0; i < 8; i++)
        pre[i] = *(const float4*)&covk[(size_t)(bh * 128 + w * 8 + i) * Aa + lane * 4];

    __syncthreads();
#pragma unroll
    for (int i = 0; i < 8; i++) {
        short4 o = {f2bf(pre[i].x), f2bf(pre[i].y), f2bf(pre[i].z), f2bf(pre[i].w)};
        *(short4*)&covT[(w * 8 + i) * DPITCH + lane * 4] = o;
    }
    __syncthreads();

    float sacc[MSZ][4];
#pragma unroll
    for (int m = 0; m < MSZ; m++)
#pragma unroll
        for (int r = 0; r < 4; r++) sacc[m][r] = 0.f;

    for (int p = 0; p < 4; p++) {
        if (p < 3) {
#pragma unroll
            for (int i = 0; i < 8; i++)
                pre[i] = *(const float4*)&covk[(size_t)(bh * 128 + (p + 1) * 32 + w * 8 + i) * Aa + lane * 4];
        }

        f32x4 acc[MSZ][2];
#pragma unroll
        for (int m = 0; m < MSZ; m++) {
            acc[m][0] = (f32x4){0.f,0.f,0.f,0.f};
            acc[m][1] = (f32x4){0.f,0.f,0.f,0.f};
        }
#pragma unroll
        for (int sg = 0; sg < 2; sg++) {
            const int a0 = w * 64 + sg * 32 + q * 8;
            bf16x8 bm0 = *(bf16x8*)&covT[il * DPITCH + a0];
            bf16x8 bm1 = *(bf16x8*)&covT[(16 + il) * DPITCH + a0];
#pragma unroll
            for (int m = 0; m < MSZ; m++) {
                bf16x8 am = *(bf16x8*)&Dlds[(m * 16 + il) * DPITCH + a0];
                acc[m][0] = __builtin_amdgcn_mfma_f32_16x16x32_bf16(am, bm0, acc[m][0], 0, 0, 0);
                acc[m][1] = __builtin_amdgcn_mfma_f32_16x16x32_bf16(am, bm1, acc[m][1], 0, 0, 0);
            }
        }
#pragma unroll
        for (int m = 0; m < MSZ; m++)
#pragma unroll
            for (int nf = 0; nf < 2; nf++) {
                const int bcol = bh * 128 + p * 32 + nf * 16 + il;
#pragma unroll
                for (int r = 0; r < 4; r++) {
                    float dv = bf2f(Dlds[(m * 16 + q * 4 + r) * DPITCH + bcol]);
                    sacc[m][r] = fmaf(dv, acc[m][nf][r], sacc[m][r]);
                }
            }
        __syncthreads();
        if (p < 3) {
#pragma unroll
            for (int i = 0; i < 8; i++) {
                short4 o = {f2bf(pre[i].x), f2bf(pre[i].y), f2bf(pre[i].z), f2bf(pre[i].w)};
                *(short4*)&covT[(w * 8 + i) * DPITCH + lane * 4] = o;
            }
            __syncthreads();
        }
    }

#pragma unroll
    for (int m = 0; m < MSZ; m++) {
#pragma unroll
        for (int r = 0; r < 4; r++) {
            float v = sacc[m][r];
            v += __shfl_xor(v, 1);
            v += __shfl_xor(v, 2);
            v += __shfl_xor(v, 4);
            v += __shfl_xor(v, 8);
            if (il == 0) red[w][m * 16 + q * 4 + r] = v;
        }
    }
    __syncthreads();
    if (t < MSZ * 16) {
        int c = c0 + t;
        if (c < Cc)
            Spart[bh * (Cc * Cc) + k * Cc + c] =
                red[0][t] + red[1][t] + red[2][t] + red[3][t];
    }
}

// ---------------- A: fused { ks (k,ch,bh) | k1 tiles | weight conversions } ---
__global__ __launch_bounds__(256) void kA(
    const float* __restrict__ s, const float* __restrict__ W1,
    const float* __restrict__ b1, const float* __restrict__ Wfc,
    const float* __restrict__ W2, const float* __restrict__ cov,
    short* __restrict__ hB, float* __restrict__ sums, float* __restrict__ Spart,
    short* __restrict__ W2b, short* __restrict__ Wfcb)
{
    __shared__ __align__(16) char smem[KS_SMEM];    // 51,712 B -> 3 blocks/CU
    // bijective swizzle: nwg=530, q=66, r=2 (m204); panel-sharing ks jobs land
    // on the same XCD -> duplicate cov panel reads become L2 hits.
    const int orig = blockIdx.x;
    const int xcd  = orig % 8;
    const int bid  = (xcd < 2 ? xcd * 67 : 2 * 67 + (xcd - 2) * 66) + orig / 8;
    const int t = threadIdx.x;
    const int w = t >> 6, l = t & 63, il = l & 15, q = l >> 4;

    if (bid < 400) {
        short* Dlds = (short*)smem;
        short* covT = (short*)(smem + KS_DBYTES);
        float (*red)[64] = (float(*)[64])(smem + KS_DBYTES + KS_CBYTES);
        const int k  = bid >> 2;
        const int ch = (bid >> 1) & 1;
        const int bh = bid & 1;
        if (ch == 0)
            ks_body2<4>(Wfc, cov, Spart, Dlds, covT, red, k, 0, bh, t, w, il, q);
        else
            ks_body2<3>(Wfc, cov, Spart, Dlds, covT, red, k, 1, bh, t, w, il, q);
    } else if (bid < 528) {
        // ---- k1 tile: h = s @ W1^T + b1, per-block stats, depth-2 prefetch ----
        const int bid2 = bid - 400;
        const int row0 = bid2 * 16;
        const int colw = w * 32;

        f32x4 acc[2];
        acc[0] = (f32x4){0.f,0.f,0.f,0.f};
        acc[1] = (f32x4){0.f,0.f,0.f,0.f};

        const float* arow = s  + (size_t)(row0 + il) * Aa;
        const float* bp0  = W1 + (size_t)(colw + il) * Aa;
        const float* bp1  = W1 + (size_t)(colw + 16 + il) * Aa;

        float4 pu0 = *(const float4*)&arow[q * 8];
        float4 pu1 = *(const float4*)&arow[q * 8 + 4];
        float4 pv0 = *(const float4*)&bp0[q * 8];
        float4 pv1 = *(const float4*)&bp0[q * 8 + 4];
        float4 px0 = *(const float4*)&bp1[q * 8];
        float4 px1 = *(const float4*)&bp1[q * 8 + 4];

#pragma unroll
        for (int ks = 0; ks < 8; ks++) {
            const float4 u0 = pu0, u1 = pu1, v0 = pv0, v1 = pv1, x0 = px0, x1 = px1;
            if (ks < 7) {
                const int k1n = (ks + 1) * 32 + q * 8;
                pu0 = *(const float4*)&arow[k1n];
                pu1 = *(const float4*)&arow[k1n + 4];
                pv0 = *(const float4*)&bp0[k1n];
                pv1 = *(const float4*)&bp0[k1n + 4];
                px0 = *(const float4*)&bp1[k1n];
                px1 = *(const float4*)&bp1[k1n + 4];
            }
            bf16x8 am;
            am[0]=f2bf(u0.x); am[1]=f2bf(u0.y); am[2]=f2bf(u0.z); am[3]=f2bf(u0.w);
            am[4]=f2bf(u1.x); am[5]=f2bf(u1.y); am[6]=f2bf(u1.z); am[7]=f2bf(u1.w);
            bf16x8 bm0;
            bm0[0]=f2bf(v0.x); bm0[1]=f2bf(v0.y); bm0[2]=f2bf(v0.z); bm0[3]=f2bf(v0.w);
            bm0[4]=f2bf(v1.x); bm0[5]=f2bf(v1.y); bm0[6]=f2bf(v1.z); bm0[7]=f2bf(v1.w);
            bf16x8 bm1;
            bm1[0]=f2bf(x0.x); bm1[1]=f2bf(x0.y); bm1[2]=f2bf(x0.z); bm1[3]=f2bf(x0.w);
            bm1[4]=f2bf(x1.x); bm1[5]=f2bf(x1.y); bm1[6]=f2bf(x1.z); bm1[7]=f2bf(x1.w);
            acc[0] = __builtin_amdgcn_mfma_f32_16x16x32_bf16(am, bm0, acc[0], 0, 0, 0);
            acc[1] = __builtin_amdgcn_mfma_f32_16x16x32_bf16(am, bm1, acc[1], 0, 0, 0);
        }

#pragma unroll
        for (int n = 0; n < 2; n++) {
            const int col = colw + n * 16 + il;
            const float bias = b1[col];
            float s1 = 0.f, s2 = 0.f;
#pragma unroll
            for (int r = 0; r < 4; r++) {
                float v = acc[n][r] + bias;
                hB[(size_t)(row0 + q * 4 + r) * LAT + col] = f2bf(v);
                s1 += v; s2 += v * v;
            }
            s1 += __shfl_xor(s1, 16); s1 += __shfl_xor(s1, 32);
            s2 += __shfl_xor(s2, 16); s2 += __shfl_xor(s2, 32);
            if (q == 0) {
                sums[bid2 * 256 + col]       = s1;
                sums[bid2 * 256 + 128 + col] = s2;
            }
        }
    } else if (bid == 528) {
        for (int i = t * 4; i < Aa * LAT; i += 1024) {
            float4 v = *(const float4*)&W2[i];
            short4 o = {f2bf(v.x), f2bf(v.y), f2bf(v.z), f2bf(v.w)};
            *(short4*)&W2b[i] = o;
        }
    } else {
        for (int i = t * 4; i < 128 * Aa; i += 1024) {
            int row = i >> 8;
            short4 o = {0, 0, 0, 0};
            if (row < Cc) {
                float4 v = *(const float4*)&Wfc[i];
                o.x = f2bf(v.x); o.y = f2bf(v.y); o.z = f2bf(v.z); o.w = f2bf(v.w);
            }
            *(short4*)&Wfcb[i] = o;
        }
    }
}

// ---------------- B: fused k3+k4 per 16-row tile (round-15 verbatim) ----------
__global__ __launch_bounds__(256) void kB(
    const short* __restrict__ hB, const float* __restrict__ sums,
    const float* __restrict__ gamma, const float* __restrict__ beta,
    const short* __restrict__ W2b, const float* __restrict__ b2,
    const short* __restrict__ Wfcb, const float* __restrict__ bfc,
    const float* __restrict__ Spart, const int* __restrict__ y,
    const float* __restrict__ ratio, float* __restrict__ out)
{
    __shared__ float scL[LAT], shL[LAT];
    __shared__ float redA[512];
    __shared__ short fLDS[16 * FPITCH];
    const int t = threadIdx.x;
    const int w = t >> 6, l = t & 63, il = l & 15, q = l >> 4;
    const int row0 = blockIdx.x * 16;

    {   // BN stats: 2-way parallel partial reduce over 128 block-partials
        const int chn = t & 127, hf = t >> 7;
        float a1 = 0.f, a2 = 0.f;
#pragma unroll 16
        for (int b = hf * 64; b < hf * 64 + 64; b++) {
            a1 += sums[b * 256 + chn];
            a2 += sums[b * 256 + 128 + chn];
        }
        redA[hf * 256 + chn]       = a1;
        redA[hf * 256 + 128 + chn] = a2;
    }
    __syncthreads();
    if (t < 128) {
        float A1 = redA[t] + redA[256 + t];
        float A2 = redA[128 + t] + redA[384 + t];
        float mu  = A1 * (1.0f / Nn);
        float var = A2 * (1.0f / Nn) - mu * mu;
        float inv = rsqrtf(var + BN_EPS);
        float sc  = gamma[t] * inv;
        scL[t] = sc;
        shL[t] = beta[t] - mu * sc;
    }
    __syncthreads();

    // ---- GEMM1: f_tile = relu(bn(h_tile) @ W2^T + b2), cols w*64..+64 ----
    f32x4 acc3[4];
#pragma unroll
    for (int n = 0; n < 4; n++) acc3[n] = (f32x4){0.f,0.f,0.f,0.f};

    const short* arow = hB + (size_t)(row0 + il) * LAT;
#pragma unroll
    for (int ks = 0; ks < 4; ks++) {
        const int k0 = ks * 32 + q * 8;
        bf16x8 ha = *(const bf16x8*)&arow[k0];
        bf16x8 am;
#pragma unroll
        for (int j = 0; j < 8; j++) {
            float fv = fmaf(bf2f(ha[j]), scL[k0 + j], shL[k0 + j]);
            am[j] = f2bf(fmaxf(fv, 0.f));
        }
#pragma unroll
        for (int n = 0; n < 4; n++) {
            const int col = w * 64 + n * 16 + il;
            bf16x8 bm = *(const bf16x8*)&W2b[(size_t)col * LAT + k0];
            acc3[n] = __builtin_amdgcn_mfma_f32_16x16x32_bf16(am, bm, acc3[n], 0, 0, 0);
        }
    }
#pragma unroll
    for (int n = 0; n < 4; n++) {
        const int col = w * 64 + n * 16 + il;
        const float bias = b2[col];
#pragma unroll
        for (int r = 0; r < 4; r++) {
            float v = fmaxf(acc3[n][r] + bias, 0.f);
            fLDS[(q * 4 + r) * FPITCH + col] = f2bf(v);
        }
    }
    __syncthreads();

    // ---- GEMM2: out_tile = f_tile @ Wfc^T, cols w*32..+32 ----
    f32x4 acc4[2];
    acc4[0] = (f32x4){0.f,0.f,0.f,0.f};
    acc4[1] = (f32x4){0.f,0.f,0.f,0.f};
#pragma unroll
    for (int ks = 0; ks < 8; ks++) {
        const int k0 = ks * 32 + q * 8;
        bf16x8 am = *(const bf16x8*)&fLDS[il * FPITCH + k0];
#pragma unroll
        for (int n = 0; n < 2; n++) {
            const int col = w * 32 + n * 16 + il;      // padded rows are zero
            bf16x8 bm = *(const bf16x8*)&Wfcb[(size_t)col * Aa + k0];
            acc4[n] = __builtin_amdgcn_mfma_f32_16x16x32_bf16(am, bm, acc4[n], 0, 0, 0);
        }
    }

    const float coef = 0.5f * ratio[0];
    const int4 yv4 = *(const int4*)&y[row0 + q * 4];
    const int yr[4] = {yv4.x, yv4.y, yv4.z, yv4.w};

#pragma unroll
    for (int n = 0; n < 2; n++) {
        const int col = w * 32 + n * 16 + il;
        if (col < Cc) {
            const float bias = bfc[col];
#pragma unroll
            for (int r = 0; r < 4; r++) {
                const float* sp = &Spart[yr[r] * Cc + col];
                float sv = sp[0] + sp[Cc * Cc];
                out[(size_t)(row0 + q * 4 + r) * Cc + col] =
                    acc4[n][r] + bias + coef * sv;
            }
        }
    }
}

extern "C" void kernel_launch(void* const* d_in, const int* in_sizes, int n_in,
                              void* d_out, int out_size, void* d_ws, size_t ws_size,
                              hipStream_t stream)
{
    const float* s     = (const float*)d_in[0];
    const int*   y     = (const int*)  d_in[1];
    const float* ratio = (const float*)d_in[2];
    const float* W1    = (const float*)d_in[3];
    const float* b1    = (const float*)d_in[4];
    const float* gamma = (const float*)d_in[5];
    const float* beta  = (const float*)d_in[6];
    const float* W2    = (const float*)d_in[7];
    const float* b2    = (const float*)d_in[8];
    const float* Wfc   = (const float*)d_in[9];
    const float* bfc   = (const float*)d_in[10];
    const float* cov   = (const float*)d_in[11];
    float* out = (float*)d_out;
    float* ws  = (float*)d_ws;

    short* hB    = (short*)(ws + OFF_HB);
    float* sums  = ws + OFF_SUMS;
    float* Spart = ws + OFF_SP;
    short* W2b   = (short*)(ws + OFF_W2B);
    short* Wfcb  = (short*)(ws + OFF_WFB);

    hipLaunchKernelGGL(kA, dim3(NWG_A), dim3(256), 0, stream,
                       s, W1, b1, Wfc, W2, cov, hB, sums, Spart, W2b, Wfcb);
    hipLaunchKernelGGL(kB, dim3(128), dim3(256), 0, stream,
                       hB, sums, gamma, beta, W2b, b2, Wfcb, bfc, Spart, y, ratio, out);
}